// Round 9
// baseline (385.026 us; speedup 1.0000x reference)
//
#include <hip/hip_runtime.h>
#include <hip/hip_bf16.h>
#include <cstdint>
#include <cstddef>

#define N_LEVELS   16
#define LOG2_T     19
#define TABLE_SIZE (1u << LOG2_T)
#define HASH_MASK  (TABLE_SIZE - 1u)
#define PRIME1     2654435761u

#define TPB 256
#define BT  64          // points per block

typedef __attribute__((ext_vector_type(8))) short short8;
typedef __attribute__((ext_vector_type(4))) float floatx4;
typedef __attribute__((ext_vector_type(2))) float f32x2;

// floor(16 * (2^(1/3))^l) in fp32 lands exactly on these integers
__device__ __forceinline__ constexpr float resf(int l) {
    constexpr float r[N_LEVELS] = {
        16.f, 20.f, 25.f, 32.f, 40.f, 50.f, 64.f, 80.f,
        101.f, 128.f, 161.f, 203.f, 256.f, 322.f, 406.f, 512.f
    };
    return r[l];
}

__device__ __forceinline__ unsigned short f2bf(float x) {
    union { float f; uint32_t u; } v; v.f = x;
    const uint32_t u = v.u;
    return (unsigned short)((u + 0x7fffu + ((u >> 16) & 1u)) >> 16);  // RNE
}

__device__ __forceinline__ uint32_t pk_bf16(float a, float b) {
#if __has_builtin(__builtin_amdgcn_cvt_pk_bf16_f32)
    typedef __attribute__((ext_vector_type(2))) __bf16 bf16x2;
    bf16x2 v = __builtin_amdgcn_cvt_pk_bf16_f32(a, b);
    uint32_t u; __builtin_memcpy(&u, &v, 4); return u;
#else
    return (uint32_t)f2bf(a) | ((uint32_t)f2bf(b) << 16);
#endif
}

// ---- XOR-swizzled LDS byte offsets ----
// (R5 lesson: banks wrap every 128 B; ~2e7 conflict cycles are structural to
// wave64 ds_read_b128. Don't chase below this level.)
__device__ __forceinline__ int fswz(int row, int cb) {   // feat: 128 B/row
    return (row << 7) + (cb ^ ((row & 7) << 4));
}
__device__ __forceinline__ int hswz(int row, int cb) {   // h: 512 B/row
    const int c = row & 7;
    return (row << 9) + (cb ^ ((c << 4) ^ (c << 6)));
}

// ---------------- weight packing into MFMA fragments ----------------
// Fragment for (tile, ktile): lane (q=l>>4, r=l&15) holds W[k = kt*32 + q*8 + j][col = tile*16 + r].
// (R5 layout, verbatim. Frags 16..31 — W0's x/y K-half — are packed but no
// longer consumed: the x/y rank-2 term moved to the phase-2 VALU epilogue.)
__global__ void pack_weights(const float* __restrict__ W0,
                             const float* __restrict__ W1,
                             const float* __restrict__ W2,
                             unsigned short* __restrict__ ws)
{
    const int f = blockIdx.x;       // 0..167
    const int lane = threadIdx.x;   // 0..63
    const int q = lane >> 4, r = lane & 15;
    int layer, kt, nt;
    if (f < 32)       { layer = 0; kt = f >> 4;        nt = f & 15; }
    else if (f < 160) { layer = 1; kt = (f - 32) >> 4; nt = (f - 32) & 15; }
    else              { layer = 2; kt = f - 160;       nt = 0; }
    unsigned short vals[8];
    #pragma unroll
    for (int j = 0; j < 8; ++j) {
        const int k = kt * 32 + q * 8 + j;
        const int n = nt * 16 + r;
        float v = 0.f;
        if (layer == 0) {
            // feat order: [enc0..enc31, x, y, zeros]; W0 rows: [x, y, enc0..enc31]
            if (k < 32)       v = W0[(2 + k) * 256 + n];
            else if (k == 32) v = W0[0 * 256 + n];
            else if (k == 33) v = W0[1 * 256 + n];
        } else if (layer == 1) {
            v = W1[k * 256 + n];
        } else {
            if (n < 3) v = W2[k * 3 + n];
        }
        vals[j] = f2bf(v);
    }
    uint4 pk;
    pk.x = (uint32_t)vals[0] | ((uint32_t)vals[1] << 16);
    pk.y = (uint32_t)vals[2] | ((uint32_t)vals[3] << 16);
    pk.z = (uint32_t)vals[4] | ((uint32_t)vals[5] << 16);
    pk.w = (uint32_t)vals[6] | ((uint32_t)vals[7] << 16);
    *(uint4*)(ws + (size_t)f * 1024 + lane * 8) = pk;
}

// ---- phase-1 encode: 4 levels of compile-time group G for one point ----
template<int G>
__device__ __forceinline__ uint4 encode4(float x, float y, const char* __restrict__ ebase)
{
    uint32_t vv[4];
    #pragma unroll
    for (int i = 0; i < 4; ++i) {
        const int l = 4 * G + i;
        const float res  = resf(l);
        const float grid = 2.0f / res;             // constexpr IEEE div (matches ref)
        const float invg = res * 0.5f;             // exact
        const float tx = (x + 1.0f) / grid;        // IEEE div feeds floor -> exact cell match
        const float ty = (y + 1.0f) / grid;
        const int bx = (int)floorf(tx);
        const int by = (int)floorf(ty);
        const float wx = (x - ((float)bx * grid - 1.0f)) * invg;
        const float wy = (y - ((float)by * grid - 1.0f)) * invg;
        const uint32_t hy0 = (uint32_t)by * PRIME1;
        const uint32_t hy1 = hy0 + PRIME1;         // (by+1)*P mod 2^32
        const uint32_t ux0 = (uint32_t)bx;
        const uint32_t ux1 = ux0 + 1u;
        const uint32_t lb = (uint32_t)l << (LOG2_T + 3);   // level table byte base
        const f32x2 e00 = *(const f32x2*)(ebase + (lb + (((ux0 ^ hy0) & HASH_MASK) << 3)));
        const f32x2 e01 = *(const f32x2*)(ebase + (lb + (((ux0 ^ hy1) & HASH_MASK) << 3)));
        const f32x2 e10 = *(const f32x2*)(ebase + (lb + (((ux1 ^ hy0) & HASH_MASK) << 3)));
        const f32x2 e11 = *(const f32x2*)(ebase + (lb + (((ux1 ^ hy1) & HASH_MASK) << 3)));
        const float owx = 1.f - wx, owy = 1.f - wy;
        const float f0 = (e00.x * owx + e10.x * wx) * owy + (e01.x * owx + e11.x * wx) * wy;
        const float f1 = (e00.y * owx + e10.y * wx) * owy + (e01.y * owx + e11.y * wx) * wy;
        vv[i] = pk_bf16(f0, f1);
    }
    uint4 v; v.x = vv[0]; v.y = vv[1]; v.z = vv[2]; v.w = vv[3];
    return v;
}

// ---- epilogue: bias + relu + bf16 pack, via packed f32 ops ----
__device__ __forceinline__ uint2 bias_relu_pk(const floatx4 a, const float4 bias)
{
    const f32x2 z = {0.f, 0.f};
    f32x2 v01 = {a[0], a[1]};
    f32x2 v23 = {a[2], a[3]};
    const f32x2 b01 = {bias.x, bias.y};
    const f32x2 b23 = {bias.z, bias.w};
    v01 += b01;                                    // v_pk_add_f32
    v23 += b23;
    v01 = __builtin_elementwise_max(v01, z);       // v_pk_max_f32
    v23 = __builtin_elementwise_max(v23, z);
    uint2 r;
    r.x = pk_bf16(v01.x, v01.y);
    r.y = pk_bf16(v23.x, v23.y);
    return r;
}

// ---------------- fused encoding + MLP ----------------
// R5 structure (proven stable). Change vs R5: layer 0 runs only the real
// K=32 (enc0..31); the x,y rank-2 term + bias is applied on the VALU in the
// epilogue with fp32 coords (closer to the fp32 reference than the old
// bf16-x MFMA path). Phase 1a (zero-fill) is deleted: phase-1b writes and
// phase-2 reads touch the identical swizzled granule set {0..3}^c per row.
__global__ __launch_bounds__(TPB, 4)
void fused_ngp_mlp(const float2* __restrict__ xy,
                   const float* __restrict__ emb,
                   const unsigned short* __restrict__ wpack,
                   const float* __restrict__ W0g,
                   const float* __restrict__ b0,
                   const float* __restrict__ b1,
                   const float* __restrict__ b2,
                   float* __restrict__ out, int npoints)
{
    // single 32 KB buffer: feat (enc half, XOR-swizzled [64][128B]) overlays
    // the low bytes of h ([64][512B], h0 then h1). Overlay safe: a barrier
    // separates the last feat read (phase-2 kt loop) from the first h0 write.
    __shared__ __attribute__((aligned(16))) unsigned char h[BT * 512];      // 32 KB
    unsigned char* feat = h;

    const int t = threadIdx.x;
    const int p0 = blockIdx.x * BT;
    const int wave = t >> 6;
    const int lane = t & 63;
    const int q = lane >> 4, r = lane & 15;

    // ---------- prefetch: fp32 coords of this lane's 4 epilogue points ----------
    // (issued at kernel start; L1/L2-hot by the time phase-2's epilogue runs)
    float cx[4], cy[4];
    #pragma unroll
    for (int nt = 0; nt < 4; ++nt) {
        const int gp2 = p0 + 16 * nt + r;
        float2 c;
        if (gp2 < npoints) c = xy[gp2];
        else { c.x = 0.f; c.y = 0.f; }
        cx[nt] = fminf(fmaxf(c.x, -1.f), 1.f);
        cy[nt] = fminf(fmaxf(c.y, -1.f), 1.f);
    }

    // ---------- phase 1: hash-grid gathers, wave-uniform compile-time level group ----------
    {
        const int p = lane;
        const int gp = p0 + p;
        float x = 0.f, y = 0.f;
        if (gp < npoints) {
            const float2 c = xy[gp];
            x = fminf(fmaxf(c.x, -1.f), 1.f);
            y = fminf(fmaxf(c.y, -1.f), 1.f);
        }
        const char* ebase = (const char*)emb;
        uint4 v;
        switch (wave) {
            case 0:  v = encode4<0>(x, y, ebase); break;
            case 1:  v = encode4<1>(x, y, ebase); break;
            case 2:  v = encode4<2>(x, y, ebase); break;
            default: v = encode4<3>(x, y, ebase); break;
        }
        *(uint4*)(feat + fswz(p, 16 * wave)) = v;   // one 16 B write: levels 4w..4w+3
    }
    __syncthreads();

    const unsigned short* w0p = wpack;
    const unsigned short* w1p = wpack + 32 * 1024;
    const unsigned short* w2p = wpack + 160 * 1024;

    // ---------- phase 2: layer 0, real K=32 only -> h0[point][neuron] ----------
    {
        floatx4 acc[4][4];   // [mti (neuron tile)][nt (point tile)]
        #pragma unroll
        for (int mti = 0; mti < 4; ++mti)
            #pragma unroll
            for (int nt = 0; nt < 4; ++nt)
                acc[mti][nt] = floatx4{0.f, 0.f, 0.f, 0.f};
        {
            short8 a[4], b[4];
            #pragma unroll
            for (int mti = 0; mti < 4; ++mti)
                a[mti] = *(const short8*)(w0p + (size_t)(wave * 4 + mti) * 1024 + lane * 8);
            #pragma unroll
            for (int nt = 0; nt < 4; ++nt)
                b[nt] = *(const short8*)(feat + fswz(16 * nt + r, 16 * q));
            #pragma unroll
            for (int mti = 0; mti < 4; ++mti)
                #pragma unroll
                for (int nt = 0; nt < 4; ++nt)
                    acc[mti][nt] = __builtin_amdgcn_mfma_f32_16x16x32_bf16(a[mti], b[nt], acc[mti][nt], 0, 0, 0);
        }
        __syncthreads();   // all feat reads done before h0 overwrites the overlay
        // C[m=neuron=(wave*4+mti)*16+4q+reg][n=point=16nt+r]
        // epilogue adds bias + x*W0x[n] + y*W0y[n] (rank-2 term, fp32)
        #pragma unroll
        for (int mti = 0; mti < 4; ++mti) {
            const int col = (wave * 4 + mti) * 16 + 4 * q;
            const float4 bias = *(const float4*)&b0[col];
            const float4 w0x  = *(const float4*)&W0g[col];        // W0 row 0 (x)
            const float4 w0y  = *(const float4*)&W0g[256 + col];  // W0 row 1 (y)
            #pragma unroll
            for (int nt = 0; nt < 4; ++nt) {
                const float x = cx[nt], y = cy[nt];
                floatx4 aa = acc[mti][nt];
                aa[0] += bias.x + x * w0x.x + y * w0y.x;
                aa[1] += bias.y + x * w0x.y + y * w0y.y;
                aa[2] += bias.z + x * w0x.z + y * w0y.z;
                aa[3] += bias.w + x * w0x.w + y * w0y.w;
                uint2 v;
                v.x = pk_bf16(fmaxf(aa[0], 0.f), fmaxf(aa[1], 0.f));
                v.y = pk_bf16(fmaxf(aa[2], 0.f), fmaxf(aa[3], 0.f));
                *(uint2*)(h + hswz(16 * nt + r, 2 * col)) = v;
            }
        }
    }
    __syncthreads();

    // ---------- phase 3: layer 1 (256 -> 256) ----------
    {
        floatx4 acc[4][4];
        #pragma unroll
        for (int mti = 0; mti < 4; ++mti)
            #pragma unroll
            for (int nt = 0; nt < 4; ++nt)
                acc[mti][nt] = floatx4{0.f, 0.f, 0.f, 0.f};
        #pragma unroll 2
        for (int kt = 0; kt < 8; ++kt) {
            short8 a[4], b[4];
            #pragma unroll
            for (int mti = 0; mti < 4; ++mti)
                a[mti] = *(const short8*)(w1p + (size_t)(kt * 16 + wave * 4 + mti) * 1024 + lane * 8);
            #pragma unroll
            for (int nt = 0; nt < 4; ++nt)
                b[nt] = *(const short8*)(h + hswz(16 * nt + r, 64 * kt + 16 * q));
            #pragma unroll
            for (int mti = 0; mti < 4; ++mti)
                #pragma unroll
                for (int nt = 0; nt < 4; ++nt)
                    acc[mti][nt] = __builtin_amdgcn_mfma_f32_16x16x32_bf16(a[mti], b[nt], acc[mti][nt], 0, 0, 0);
        }
        __syncthreads();   // all reads of h0 done before overwrite
        #pragma unroll
        for (int mti = 0; mti < 4; ++mti) {
            const int col = (wave * 4 + mti) * 16 + 4 * q;
            const float4 bias = *(const float4*)&b1[col];
            #pragma unroll
            for (int nt = 0; nt < 4; ++nt) {
                const uint2 v = bias_relu_pk(acc[mti][nt], bias);
                *(uint2*)(h + hswz(16 * nt + r, 2 * col)) = v;
            }
        }
    }
    __syncthreads();

    // ---------- phase 4: layer 2 (256 -> 3), sigmoid, store ----------
    {
        floatx4 acc = floatx4{0.f, 0.f, 0.f, 0.f};
        #pragma unroll
        for (int kt = 0; kt < 8; ++kt) {
            const short8 a = *(const short8*)(w2p + (size_t)kt * 1024 + lane * 8);
            const short8 b = *(const short8*)(h + hswz(16 * wave + r, 64 * kt + 16 * q));
            acc = __builtin_amdgcn_mfma_f32_16x16x32_bf16(a, b, acc, 0, 0, 0);
        }
        // C[m=4q+reg][n=16*wave+r]: only q==0, reg<3 are real outputs
        if (q == 0) {
            const int gp = p0 + 16 * wave + r;
            if (gp < npoints) {
                #pragma unroll
                for (int reg = 0; reg < 3; ++reg) {
                    const float s = acc[reg] + b2[reg];
                    out[(size_t)gp * 3 + reg] = 1.f / (1.f + expf(-s));
                }
            }
        }
    }
}

extern "C" void kernel_launch(void* const* d_in, const int* in_sizes, int n_in,
                              void* d_out, int out_size, void* d_ws, size_t ws_size,
                              hipStream_t stream) {
    const float* coord = (const float*)d_in[0];
    const float* emb   = (const float*)d_in[1];
    const float* W0    = (const float*)d_in[2];
    const float* b0    = (const float*)d_in[3];
    const float* W1    = (const float*)d_in[4];
    const float* b1    = (const float*)d_in[5];
    const float* W2    = (const float*)d_in[6];
    const float* b2    = (const float*)d_in[7];
    float* out = (float*)d_out;
    unsigned short* ws = (unsigned short*)d_ws;

    const int npoints = in_sizes[0] / 2;
    const int blocks  = (npoints + BT - 1) / BT;

    hipLaunchKernelGGL(pack_weights, dim3(168), dim3(64), 0, stream, W0, W1, W2, ws);
    hipLaunchKernelGGL(fused_ngp_mlp, dim3(blocks), dim3(TPB), 0, stream,
                       (const float2*)coord, emb, ws, W0, b0, b1, b2, out, npoints);
}

// Round 10
// 358.613 us; speedup vs baseline: 1.0737x; 1.0737x over previous
//
#include <hip/hip_runtime.h>
#include <hip/hip_bf16.h>
#include <cstdint>
#include <cstddef>

#define N_LEVELS   16
#define LOG2_T     19
#define TABLE_SIZE (1u << LOG2_T)
#define HASH_MASK  (TABLE_SIZE - 1u)
#define PRIME1     2654435761u

#define TPB 256
#define BT  64          // points per block

#define W_BYTES    344064                     // 168 frags * 2048 B
#define DENSE_TOT  716544                     // sum of (res+2)^2 over levels

typedef __attribute__((ext_vector_type(8))) short short8;
typedef __attribute__((ext_vector_type(4))) float floatx4;
typedef __attribute__((ext_vector_type(2))) float f32x2;
typedef float f32x4u __attribute__((ext_vector_type(4), aligned(8)));  // 8B-aligned 16B load

// floor(16 * (2^(1/3))^l) in fp32 lands exactly on these integers
__device__ __forceinline__ constexpr float resf(int l) {
    constexpr float r[N_LEVELS] = {
        16.f, 20.f, 25.f, 32.f, 40.f, 50.f, 64.f, 80.f,
        101.f, 128.f, 161.f, 203.f, 256.f, 322.f, 406.f, 512.f
    };
    return r[l];
}
// dense per-level dims (res+2) and entry offsets
__device__ __forceinline__ constexpr int dimf(int l) {
    constexpr int d[N_LEVELS] = {18,22,27,34,42,52,66,82,103,130,163,205,258,324,408,514};
    return d[l];
}
__device__ __forceinline__ constexpr int offf(int l) {
    constexpr int o[N_LEVELS] = {0,324,808,1537,2693,4457,7161,11517,
                                 18241,28850,45750,72319,114344,180908,285884,452348};
    return o[l];
}

__device__ __forceinline__ unsigned short f2bf(float x) {
    union { float f; uint32_t u; } v; v.f = x;
    const uint32_t u = v.u;
    return (unsigned short)((u + 0x7fffu + ((u >> 16) & 1u)) >> 16);  // RNE
}

__device__ __forceinline__ uint32_t pk_bf16(float a, float b) {
#if __has_builtin(__builtin_amdgcn_cvt_pk_bf16_f32)
    typedef __attribute__((ext_vector_type(2))) __bf16 bf16x2;
    bf16x2 v = __builtin_amdgcn_cvt_pk_bf16_f32(a, b);
    uint32_t u; __builtin_memcpy(&u, &v, 4); return u;
#else
    return (uint32_t)f2bf(a) | ((uint32_t)f2bf(b) << 16);
#endif
}

// ---- XOR-swizzled LDS byte offsets ----
// (R5 lesson: banks wrap every 128 B; ~2e7 conflict cycles are structural to
// wave64 ds_read_b128. Don't chase below this level.)
__device__ __forceinline__ int fswz(int row, int cb) {   // feat: 128 B/row
    return (row << 7) + (cb ^ ((row & 7) << 4));
}
__device__ __forceinline__ int hswz(int row, int cb) {   // h: 512 B/row
    const int c = row & 7;
    return (row << 9) + (cb ^ ((c << 4) ^ (c << 6)));
}

// ---------------- dense table build (integer-only re-index) ----------------
// dense[l][uy][ux] = emb[l][(ux ^ uy*PRIME1) & mask] — exact same float bits
// the reference would gather. Makes x-corner pairs ADJACENT (one 16B load)
// and shrinks the hot footprint 64 MB -> 5.7 MB (L2-resident).
__global__ void k_dense(const float* __restrict__ emb, f32x2* __restrict__ dense, int total)
{
    const int i = blockIdx.x * 256 + threadIdx.x;
    if (i >= total) return;
    const f32x2* e2 = (const f32x2*)emb;
#define DL(L, NEXT)                                                          \
    if (i < (NEXT)) {                                                        \
        const int local = i - offf(L);                                       \
        const int uy = local / dimf(L);                                      \
        const int ux = local - uy * dimf(L);                                 \
        const uint32_t h = ((uint32_t)ux ^ ((uint32_t)uy * PRIME1)) & HASH_MASK; \
        dense[i] = e2[(size_t)(L) * TABLE_SIZE + h];                         \
        return;                                                              \
    }
    DL(0,  324)     DL(1,  808)     DL(2,  1537)    DL(3,  2693)
    DL(4,  4457)    DL(5,  7161)    DL(6,  11517)   DL(7,  18241)
    DL(8,  28850)   DL(9,  45750)   DL(10, 72319)   DL(11, 114344)
    DL(12, 180908)  DL(13, 285884)  DL(14, 452348)  DL(15, 716544)
#undef DL
}

// ---------------- weight packing into MFMA fragments ----------------
// Fragment for (tile, ktile): lane (q=l>>4, r=l&15) holds W[k = kt*32 + q*8 + j][col = tile*16 + r].
__global__ void pack_weights(const float* __restrict__ W0,
                             const float* __restrict__ W1,
                             const float* __restrict__ W2,
                             unsigned short* __restrict__ ws)
{
    const int f = blockIdx.x;       // 0..167
    const int lane = threadIdx.x;   // 0..63
    const int q = lane >> 4, r = lane & 15;
    int layer, kt, nt;
    if (f < 32)       { layer = 0; kt = f >> 4;        nt = f & 15; }
    else if (f < 160) { layer = 1; kt = (f - 32) >> 4; nt = (f - 32) & 15; }
    else              { layer = 2; kt = f - 160;       nt = 0; }
    unsigned short vals[8];
    #pragma unroll
    for (int j = 0; j < 8; ++j) {
        const int k = kt * 32 + q * 8 + j;
        const int n = nt * 16 + r;
        float v = 0.f;
        if (layer == 0) {
            // feat order: [enc0..enc31, x, y, zeros]; W0 rows: [x, y, enc0..enc31]
            if (k < 32)       v = W0[(2 + k) * 256 + n];
            else if (k == 32) v = W0[0 * 256 + n];
            else if (k == 33) v = W0[1 * 256 + n];
        } else if (layer == 1) {
            v = W1[k * 256 + n];
        } else {
            if (n < 3) v = W2[k * 3 + n];
        }
        vals[j] = f2bf(v);
    }
    uint4 pk;
    pk.x = (uint32_t)vals[0] | ((uint32_t)vals[1] << 16);
    pk.y = (uint32_t)vals[2] | ((uint32_t)vals[3] << 16);
    pk.z = (uint32_t)vals[4] | ((uint32_t)vals[5] << 16);
    pk.w = (uint32_t)vals[6] | ((uint32_t)vals[7] << 16);
    *(uint4*)(ws + (size_t)f * 1024 + lane * 8) = pk;
}

// ---- phase-1 encode, DENSE path: 4 levels, x-corner pairs as one 16B load ----
template<int G>
__device__ __forceinline__ uint4 encode4d(float x, float y, const f32x2* __restrict__ dense)
{
    uint32_t vv[4];
    #pragma unroll
    for (int i = 0; i < 4; ++i) {
        const int l = 4 * G + i;
        const float res  = resf(l);
        const float grid = 2.0f / res;             // constexpr IEEE div (matches ref)
        const float invg = res * 0.5f;             // exact
        const float tx = (x + 1.0f) / grid;        // IEEE div feeds floor -> exact cell match
        const float ty = (y + 1.0f) / grid;
        const int bx = (int)floorf(tx);
        const int by = (int)floorf(ty);
        const float wx = (x - ((float)bx * grid - 1.0f)) * invg;
        const float wy = (y - ((float)by * grid - 1.0f)) * invg;
        const int base = offf(l) + by * dimf(l) + bx;          // entry index
        const f32x4u r0 = *(const f32x4u*)(dense + base);            // e00=.xy e10=.zw
        const f32x4u r1 = *(const f32x4u*)(dense + base + dimf(l));  // e01=.xy e11=.zw
        const float owx = 1.f - wx, owy = 1.f - wy;
        const float f0 = (r0.x * owx + r0.z * wx) * owy + (r1.x * owx + r1.z * wx) * wy;
        const float f1 = (r0.y * owx + r0.w * wx) * owy + (r1.y * owx + r1.w * wx) * wy;
        vv[i] = pk_bf16(f0, f1);
    }
    uint4 v; v.x = vv[0]; v.y = vv[1]; v.z = vv[2]; v.w = vv[3];
    return v;
}

// ---- phase-1 encode, HASH fallback (R5 verbatim) ----
template<int G>
__device__ __forceinline__ uint4 encode4h(float x, float y, const char* __restrict__ ebase)
{
    uint32_t vv[4];
    #pragma unroll
    for (int i = 0; i < 4; ++i) {
        const int l = 4 * G + i;
        const float res  = resf(l);
        const float grid = 2.0f / res;
        const float invg = res * 0.5f;
        const float tx = (x + 1.0f) / grid;
        const float ty = (y + 1.0f) / grid;
        const int bx = (int)floorf(tx);
        const int by = (int)floorf(ty);
        const float wx = (x - ((float)bx * grid - 1.0f)) * invg;
        const float wy = (y - ((float)by * grid - 1.0f)) * invg;
        const uint32_t hy0 = (uint32_t)by * PRIME1;
        const uint32_t hy1 = hy0 + PRIME1;
        const uint32_t ux0 = (uint32_t)bx;
        const uint32_t ux1 = ux0 + 1u;
        const uint32_t lb = (uint32_t)l << (LOG2_T + 3);
        const f32x2 e00 = *(const f32x2*)(ebase + (lb + (((ux0 ^ hy0) & HASH_MASK) << 3)));
        const f32x2 e01 = *(const f32x2*)(ebase + (lb + (((ux0 ^ hy1) & HASH_MASK) << 3)));
        const f32x2 e10 = *(const f32x2*)(ebase + (lb + (((ux1 ^ hy0) & HASH_MASK) << 3)));
        const f32x2 e11 = *(const f32x2*)(ebase + (lb + (((ux1 ^ hy1) & HASH_MASK) << 3)));
        const float owx = 1.f - wx, owy = 1.f - wy;
        const float f0 = (e00.x * owx + e10.x * wx) * owy + (e01.x * owx + e11.x * wx) * wy;
        const float f1 = (e00.y * owx + e10.y * wx) * owy + (e01.y * owx + e11.y * wx) * wy;
        vv[i] = pk_bf16(f0, f1);
    }
    uint4 v; v.x = vv[0]; v.y = vv[1]; v.z = vv[2]; v.w = vv[3];
    return v;
}

// ---- epilogue: bias + relu + bf16 pack, via packed f32 ops ----
__device__ __forceinline__ uint2 bias_relu_pk(const floatx4 a, const float4 bias)
{
    const f32x2 z = {0.f, 0.f};
    f32x2 v01 = {a[0], a[1]};
    f32x2 v23 = {a[2], a[3]};
    const f32x2 b01 = {bias.x, bias.y};
    const f32x2 b23 = {bias.z, bias.w};
    v01 += b01;                                    // v_pk_add_f32
    v23 += b23;
    v01 = __builtin_elementwise_max(v01, z);       // v_pk_max_f32
    v23 = __builtin_elementwise_max(v23, z);
    uint2 r;
    r.x = pk_bf16(v01.x, v01.y);
    r.y = pk_bf16(v23.x, v23.y);
    return r;
}

// ---------------- fused encoding + MLP (R5 structure verbatim) ----------------
template<bool DENSE>
__global__ __launch_bounds__(TPB, 4)
void fused_ngp_mlp(const float2* __restrict__ xy,
                   const float* __restrict__ emb,
                   const f32x2* __restrict__ dense,
                   const unsigned short* __restrict__ wpack,
                   const float* __restrict__ b0,
                   const float* __restrict__ b1,
                   const float* __restrict__ b2,
                   float* __restrict__ out, int npoints)
{
    // single 32 KB buffer: feat (8 KB, XOR-swizzled [64][128B]) overlays the
    // low bytes of h ([64][512B], h0 then h1). Overlay safe: a barrier
    // separates the last feat read (phase-2 kt loop) from the first h0 write.
    __shared__ __attribute__((aligned(16))) unsigned char h[BT * 512];      // 32 KB
    unsigned char* feat = h;

    const int t = threadIdx.x;
    const int p0 = blockIdx.x * BT;
    const int wave = t >> 6;
    const int lane = t & 63;
    const int q = lane >> 4, r = lane & 15;

    // ---------- phase 1a: x,y + zero fill (bytes 64..127 of each feat row) ----------
    {
        const int p = t >> 2;          // 0..63
        const int sg = t & 3;
        const int gp = p0 + p;
        float x = 0.f, y = 0.f;
        if (gp < npoints) {
            const float2 c = xy[gp];
            x = fminf(fmaxf(c.x, -1.f), 1.f);
            y = fminf(fmaxf(c.y, -1.f), 1.f);
        }
        uint4 z = {0u, 0u, 0u, 0u};
        if (sg == 0) z.x = pk_bf16(x, y);
        *(uint4*)(feat + fswz(p, 64 + 16 * sg)) = z;
    }

    // ---------- phase 1b: grid gathers, wave-uniform compile-time level group ----------
    {
        const int p = lane;
        const int gp = p0 + p;
        float x = 0.f, y = 0.f;
        if (gp < npoints) {
            const float2 c = xy[gp];
            x = fminf(fmaxf(c.x, -1.f), 1.f);
            y = fminf(fmaxf(c.y, -1.f), 1.f);
        }
        uint4 v;
        if (DENSE) {
            switch (wave) {
                case 0:  v = encode4d<0>(x, y, dense); break;
                case 1:  v = encode4d<1>(x, y, dense); break;
                case 2:  v = encode4d<2>(x, y, dense); break;
                default: v = encode4d<3>(x, y, dense); break;
            }
        } else {
            const char* ebase = (const char*)emb;
            switch (wave) {
                case 0:  v = encode4h<0>(x, y, ebase); break;
                case 1:  v = encode4h<1>(x, y, ebase); break;
                case 2:  v = encode4h<2>(x, y, ebase); break;
                default: v = encode4h<3>(x, y, ebase); break;
            }
        }
        *(uint4*)(feat + fswz(p, 16 * wave)) = v;   // one 16 B write: levels 4w..4w+3
    }
    __syncthreads();

    const unsigned short* w0p = wpack;
    const unsigned short* w1p = wpack + 32 * 1024;
    const unsigned short* w2p = wpack + 160 * 1024;

    // ---------- phase 2: layer 0 (K=64 padded), W^T x feat^T -> h0[point][neuron] ----------
    {
        floatx4 acc[4][4];   // [mti (neuron tile)][nt (point tile)]
        #pragma unroll
        for (int mti = 0; mti < 4; ++mti)
            #pragma unroll
            for (int nt = 0; nt < 4; ++nt)
                acc[mti][nt] = floatx4{0.f, 0.f, 0.f, 0.f};
        #pragma unroll
        for (int kt = 0; kt < 2; ++kt) {
            short8 a[4], b[4];
            #pragma unroll
            for (int mti = 0; mti < 4; ++mti)
                a[mti] = *(const short8*)(w0p + (size_t)(kt * 16 + wave * 4 + mti) * 1024 + lane * 8);
            #pragma unroll
            for (int nt = 0; nt < 4; ++nt)
                b[nt] = *(const short8*)(feat + fswz(16 * nt + r, 64 * kt + 16 * q));
            #pragma unroll
            for (int mti = 0; mti < 4; ++mti)
                #pragma unroll
                for (int nt = 0; nt < 4; ++nt)
                    acc[mti][nt] = __builtin_amdgcn_mfma_f32_16x16x32_bf16(a[mti], b[nt], acc[mti][nt], 0, 0, 0);
        }
        __syncthreads();   // all feat reads done before h0 overwrites the overlay
        // C[m=neuron=(wave*4+mti)*16+4q+reg][n=point=16nt+r]
        #pragma unroll
        for (int mti = 0; mti < 4; ++mti) {
            const int col = (wave * 4 + mti) * 16 + 4 * q;
            const float4 bias = *(const float4*)&b0[col];
            #pragma unroll
            for (int nt = 0; nt < 4; ++nt) {
                const uint2 v = bias_relu_pk(acc[mti][nt], bias);
                *(uint2*)(h + hswz(16 * nt + r, 2 * col)) = v;
            }
        }
    }
    __syncthreads();

    // ---------- phase 3: layer 1 (256 -> 256) ----------
    {
        floatx4 acc[4][4];
        #pragma unroll
        for (int mti = 0; mti < 4; ++mti)
            #pragma unroll
            for (int nt = 0; nt < 4; ++nt)
                acc[mti][nt] = floatx4{0.f, 0.f, 0.f, 0.f};
        #pragma unroll 2
        for (int kt = 0; kt < 8; ++kt) {
            short8 a[4], b[4];
            #pragma unroll
            for (int mti = 0; mti < 4; ++mti)
                a[mti] = *(const short8*)(w1p + (size_t)(kt * 16 + wave * 4 + mti) * 1024 + lane * 8);
            #pragma unroll
            for (int nt = 0; nt < 4; ++nt)
                b[nt] = *(const short8*)(h + hswz(16 * nt + r, 64 * kt + 16 * q));
            #pragma unroll
            for (int mti = 0; mti < 4; ++mti)
                #pragma unroll
                for (int nt = 0; nt < 4; ++nt)
                    acc[mti][nt] = __builtin_amdgcn_mfma_f32_16x16x32_bf16(a[mti], b[nt], acc[mti][nt], 0, 0, 0);
        }
        __syncthreads();   // all reads of h0 done before overwrite
        #pragma unroll
        for (int mti = 0; mti < 4; ++mti) {
            const int col = (wave * 4 + mti) * 16 + 4 * q;
            const float4 bias = *(const float4*)&b1[col];
            #pragma unroll
            for (int nt = 0; nt < 4; ++nt) {
                const uint2 v = bias_relu_pk(acc[mti][nt], bias);
                *(uint2*)(h + hswz(16 * nt + r, 2 * col)) = v;
            }
        }
    }
    __syncthreads();

    // ---------- phase 4: layer 2 (256 -> 3), sigmoid, store ----------
    {
        floatx4 acc = floatx4{0.f, 0.f, 0.f, 0.f};
        #pragma unroll
        for (int kt = 0; kt < 8; ++kt) {
            const short8 a = *(const short8*)(w2p + (size_t)kt * 1024 + lane * 8);
            const short8 b = *(const short8*)(h + hswz(16 * wave + r, 64 * kt + 16 * q));
            acc = __builtin_amdgcn_mfma_f32_16x16x32_bf16(a, b, acc, 0, 0, 0);
        }
        // C[m=4q+reg][n=16*wave+r]: only q==0, reg<3 are real outputs
        if (q == 0) {
            const int gp = p0 + 16 * wave + r;
            if (gp < npoints) {
                #pragma unroll
                for (int reg = 0; reg < 3; ++reg) {
                    const float s = acc[reg] + b2[reg];
                    out[(size_t)gp * 3 + reg] = 1.f / (1.f + expf(-s));
                }
            }
        }
    }
}

extern "C" void kernel_launch(void* const* d_in, const int* in_sizes, int n_in,
                              void* d_out, int out_size, void* d_ws, size_t ws_size,
                              hipStream_t stream) {
    const float* coord = (const float*)d_in[0];
    const float* emb   = (const float*)d_in[1];
    const float* W0    = (const float*)d_in[2];
    const float* b0    = (const float*)d_in[3];
    const float* W1    = (const float*)d_in[4];
    const float* b1    = (const float*)d_in[5];
    const float* W2    = (const float*)d_in[6];
    const float* b2    = (const float*)d_in[7];
    float* out = (float*)d_out;
    unsigned char* ws = (unsigned char*)d_ws;

    const int npoints = in_sizes[0] / 2;
    const int blocks  = (npoints + BT - 1) / BT;

    unsigned short* wp = (unsigned short*)ws;
    hipLaunchKernelGGL(pack_weights, dim3(168), dim3(64), 0, stream, W0, W1, W2, wp);

    const size_t required = (size_t)W_BYTES + (size_t)DENSE_TOT * 8;
    if (ws_size >= required) {
        f32x2* dense = (f32x2*)(ws + W_BYTES);
        hipLaunchKernelGGL(k_dense, dim3((DENSE_TOT + 255) / 256), dim3(256), 0, stream,
                           emb, dense, DENSE_TOT);
        hipLaunchKernelGGL((fused_ngp_mlp<true>), dim3(blocks), dim3(TPB), 0, stream,
                           (const float2*)coord, emb, dense, wp, b0, b1, b2, out, npoints);
    } else {
        hipLaunchKernelGGL((fused_ngp_mlp<false>), dim3(blocks), dim3(TPB), 0, stream,
                           (const float2*)coord, emb, (const f32x2*)nullptr, wp, b0, b1, b2, out, npoints);
    }
}